// Round 14
// baseline (30.875 us; speedup 1.0000x reference)
//
#include <hip/hip_runtime.h>
#include <math.h>

// CapLayer fused, R14: W never touches LDS. Lane (g,c) owns W[g,4c..4c+3,:]
// which is CONTIGUOUS in Wt (32 floats at g*1280+j*128+4c*8) -> 8 float4
// global loads + 1 bias float4 into registers. s-partial and u-phase both
// consume the same register slice; u[g,k] completed by DPP quad-reduce
// (replaces 12 ds_read_b128 + 12-exchange gather). LDS = 2 tiny s/esum
// buffers (~300B). DS ops/thread ~150 -> ~70 (R13 showed DS-pipe is the
// binding resource: DPP xor1/2 conversion alone gave -6%).
// NO launch_bounds min-waves (R2/R3/R7: VGPR caps below working set spill).

#define G_    32
#define J_    10
#define D_    16
#define NT_   128

__device__ __forceinline__ float dpp_add_x1(float v) {   // v += lane^1 partner
    const int s = __builtin_amdgcn_update_dpp(0, __float_as_int(v), 0xB1, 0xF, 0xF, true);
    return v + __int_as_float(s);
}
__device__ __forceinline__ float dpp_add_x2(float v) {   // v += lane^2 partner
    const int s = __builtin_amdgcn_update_dpp(0, __float_as_int(v), 0x4E, 0xF, 0xF, true);
    return v + __int_as_float(s);
}

__global__ __launch_bounds__(NT_) void caps_route_kernel(
    const float* __restrict__ x,     // (b, g*8+k, s) flat b*9216 + g*288 + k*36 + s
    const float* __restrict__ Wt,    // (g, j*16+d, k) flat g*1280 + (j*16+d)*8 + k
    const float* __restrict__ bias,  // g*160 + j*16 + d
    float* __restrict__ out)         // (b, j, d)
{
    const int B = blockIdx.x, nwg = gridDim.x;
    const int bj = ((nwg & 7) == 0) ? (B & 7) * (nwg >> 3) + (B >> 3) : B;
    const int b = bj / J_, j = bj - b * J_;
    const int t = threadIdx.x;
    const int lane = t & 63, wid = t >> 6;
    const int g = t >> 2, c = t & 3;     // group 0..31, 4 lanes/group

    __shared__ __align__(16) float swl[2][2][D_]; // [buf][wave][d] s-partials
    __shared__ float esw[2][2];                   // [buf][wave] exp-sum partials

    // ---- W slice into registers: Wreg[m][k] = W[g, 4c+m, k] ----
    float Wreg[4][8];
    float br[4];
    {
        const float* wsrc = Wt + (size_t)g * 1280 + j * 128 + (4 * c) * 8;
        #pragma unroll
        for (int m = 0; m < 4; ++m) {
            const float4 a0 = *(const float4*)(wsrc + m * 8);
            const float4 a1 = *(const float4*)(wsrc + m * 8 + 4);
            Wreg[m][0] = a0.x; Wreg[m][1] = a0.y; Wreg[m][2] = a0.z; Wreg[m][3] = a0.w;
            Wreg[m][4] = a1.x; Wreg[m][5] = a1.y; Wreg[m][6] = a1.z; Wreg[m][7] = a1.w;
        }
        const float4 bb = *(const float4*)(bias + (size_t)g * 160 + j * 16 + 4 * c);
        br[0] = bb.x; br[1] = bb.y; br[2] = bb.z; br[3] = bb.w;
    }

    // ---- x preload: 2 aligned float4 + 1 scalar per k (lane c owns
    //      s in {4c..4c+3, 16+4c..19+4c, 32+c}) ----
    float xv[8][9];
    {
        const float* xb = x + (size_t)b * 9216 + (size_t)g * 288 + 4 * c;
        #pragma unroll
        for (int k = 0; k < 8; ++k) {
            const float4 a0 = *(const float4*)(xb + k * 36);
            const float4 a1 = *(const float4*)(xb + k * 36 + 16);
            xv[k][0] = a0.x; xv[k][1] = a0.y; xv[k][2] = a0.z; xv[k][3] = a0.w;
            xv[k][4] = a1.x; xv[k][5] = a1.y; xv[k][6] = a1.z; xv[k][7] = a1.w;
            xv[k][8] = xb[k * 36 + 32 - 3 * c];   // = row + 32 + c
        }
    }

    float b_loc[9] = {0.f,0.f,0.f,0.f,0.f,0.f,0.f,0.f,0.f};
    const float EPS = 2.220446049250313e-16f;

    #pragma unroll 1
    for (int it = 0; it < 3; ++it) {
        const int kb = it & 1;

        // ---- e-weighted x sums over this thread's 9 s's ----
        float yp[8] = {0.f,0.f,0.f,0.f,0.f,0.f,0.f,0.f};
        float esum = 0.f;
        if (it == 0) {
            #pragma unroll
            for (int q = 0; q < 9; ++q) {
                #pragma unroll
                for (int k = 0; k < 8; ++k) yp[k] += xv[k][q];
            }
        } else {
            #pragma unroll
            for (int q = 0; q < 9; ++q) {
                const float e = __expf(b_loc[q]);
                esum += e;
                #pragma unroll
                for (int k = 0; k < 8; ++k) yp[k] += e * xv[k][q];
            }
        }
        // quad reduce via DPP: every lane gets y[g][k] and C_g
        #pragma unroll
        for (int k = 0; k < 8; ++k) {
            yp[k] = dpp_add_x1(yp[k]);
            yp[k] = dpp_add_x2(yp[k]);
        }
        if (it > 0) { esum = dpp_add_x1(esum); esum = dpp_add_x2(esum); }
        const float cg = (it == 0) ? 36.f : esum;

        // ---- per-lane s-partial for d = 4c..4c+3 (registers only) ----
        float part[4];
        #pragma unroll
        for (int m = 0; m < 4; ++m) {
            float p = br[m] * cg;
            #pragma unroll
            for (int k = 0; k < 8; ++k) p += Wreg[m][k] * yp[k];
            part[m] = p;
        }
        // butterfly over g-bits (xor 4,8,16,32): sums the wave's 16 groups
        #pragma unroll
        for (int off = 4; off <= 32; off <<= 1) {
            #pragma unroll
            for (int m = 0; m < 4; ++m) part[m] += __shfl_xor(part[m], off);
            if (it > 0) esum += __shfl_xor(esum, off);
        }
        // lanes 0..3 hold s_w[4c..4c+3] (c == lane there)
        if (lane < 4) {
            float4 pw; pw.x = part[0]; pw.y = part[1]; pw.z = part[2]; pw.w = part[3];
            *(float4*)(&swl[kb][wid][4 * lane]) = pw;
            if (lane == 0) esw[kb][wid] = esum;
        }
        __syncthreads();                           // 1 barrier per iter

        const float denom = (it == 0) ? 1152.f : (esw[kb][0] + esw[kb][1]);

        // ---- this lane's s slice (broadcast b128 reads, both waves) ----
        const float4 sa = *(const float4*)(&swl[kb][0][4 * c]);
        const float4 sb = *(const float4*)(&swl[kb][1][4 * c]);
        float s4[4];
        s4[0] = sa.x + sb.x; s4[1] = sa.y + sb.y;
        s4[2] = sa.z + sb.z; s4[3] = sa.w + sb.w;

        // ssq: slice partial + quad reduce (every lane gets full ssq)
        float ssq = s4[0]*s4[0] + s4[1]*s4[1] + s4[2]*s4[2] + s4[3]*s4[3];
        ssq = dpp_add_x1(ssq);
        ssq = dpp_add_x2(ssq);

        const float alpha = 1.f / denom;
        const float n2    = ssq * alpha * alpha;
        const float nrm   = sqrtf(n2);
        const float coeff = (n2 / (1.f + n2)) / (nrm + EPS);
        const float beta  = alpha * coeff;        // v[d] = s_unnorm[d] * beta

        if (it < 2) {
            // ---- u[g,k]: per-lane partial over d-slice, DPP quad reduce ----
            const float t0 = s4[0] * beta, t1 = s4[1] * beta;
            const float t2 = s4[2] * beta, t3 = s4[3] * beta;
            float uk[8];
            #pragma unroll
            for (int k = 0; k < 8; ++k) {
                float uu = t0 * Wreg[0][k] + t1 * Wreg[1][k]
                         + t2 * Wreg[2][k] + t3 * Wreg[3][k];
                uu = dpp_add_x1(uu);
                uk[k] = dpp_add_x2(uu);
            }
            float u8 = t0 * br[0] + t1 * br[1] + t2 * br[2] + t3 * br[3];
            u8 = dpp_add_x1(u8);
            u8 = dpp_add_x2(u8);

            // ---- b_i += u . x_i + u_bias ----
            #pragma unroll
            for (int q = 0; q < 9; ++q) {
                float acc = u8;
                #pragma unroll
                for (int k = 0; k < 8; ++k) acc += uk[k] * xv[k][q];
                b_loc[q] += acc;
            }
        } else {
            if (t < D_) {
                const float sd = swl[kb][0][t] + swl[kb][1][t];
                out[(size_t)bj * D_ + t] = sd * beta;
            }
        }
    }
}

extern "C" void kernel_launch(void* const* d_in, const int* in_sizes, int n_in,
                              void* d_out, int out_size, void* d_ws, size_t ws_size,
                              hipStream_t stream) {
    const float* x    = (const float*)d_in[0];
    const float* Wt   = (const float*)d_in[1];
    const float* bias = (const float*)d_in[2];
    float* out        = (float*)d_out;

    const int bs = in_sizes[0] / 9216;   // 256
    dim3 grid(bs * J_);                  // 2560
    dim3 block(NT_);
    caps_route_kernel<<<grid, block, 0, stream>>>(x, Wt, bias, out);
}

// Round 15
// 23.711 us; speedup vs baseline: 1.3022x; 1.3022x over previous
//
#include <hip/hip_runtime.h>
#include <math.h>

// CapLayer fused, R15 = R13 + two DS-pipe cuts (DS pipe is per-CU; model:
// R12 ~1500 cyc/wave service x 20 waves = 12.5us, matches the ~25us plateau;
// R13's -350 cyc gave -1.5us; R14 proved VGPR>128 halves occupancy and loses).
//  1. u-phase: per-lane d-slice partials via ONE ds_read_b128 per k (9/iter)
//     + DPP quad-reduce -> replaces 48 scalar ds_reads + 8-bperm gather.
//  2. butterfly xor4/xor8 -> DPP row_ror:4/8 (rotation == xor for full-group
//     sums); only xor16/32 remain bpermute.
// W stays in LDS (VGPR ~116, 16 waves/CU bin). Layout [g][k][d] stride 148.
// NO launch_bounds min-waves (R2/R3/R7: caps below working set spill).

#define G_    32
#define J_    10
#define D_    16
#define NT_   128
#define GSW_  148

__device__ __forceinline__ float dpp_add_x1(float v) {   // v += lane^1
    const int s = __builtin_amdgcn_update_dpp(0, __float_as_int(v), 0xB1, 0xF, 0xF, true);
    return v + __int_as_float(s);
}
__device__ __forceinline__ float dpp_add_x2(float v) {   // v += lane^2
    const int s = __builtin_amdgcn_update_dpp(0, __float_as_int(v), 0x4E, 0xF, 0xF, true);
    return v + __int_as_float(s);
}
__device__ __forceinline__ float dpp_add_ror4(float v) { // v += row_ror:4
    const int s = __builtin_amdgcn_update_dpp(0, __float_as_int(v), 0x124, 0xF, 0xF, true);
    return v + __int_as_float(s);
}
__device__ __forceinline__ float dpp_add_ror8(float v) { // v += row_ror:8
    const int s = __builtin_amdgcn_update_dpp(0, __float_as_int(v), 0x128, 0xF, 0xF, true);
    return v + __int_as_float(s);
}

__global__ __launch_bounds__(NT_) void caps_route_kernel(
    const float* __restrict__ x,     // (b, g*8+k, s) flat b*9216 + g*288 + k*36 + s
    const float* __restrict__ Wt,    // (g, j*16+d, k) flat g*1280 + (j*16+d)*8 + k
    const float* __restrict__ bias,  // g*160 + j*16 + d
    float* __restrict__ out)         // (b, j, d)
{
    const int B = blockIdx.x, nwg = gridDim.x;
    const int bj = ((nwg & 7) == 0) ? (B & 7) * (nwg >> 3) + (B >> 3) : B;
    const int b = bj / J_, j = bj - b * J_;
    const int t = threadIdx.x;
    const int lane = t & 63, wid = t >> 6;
    const int g = t >> 2, c = t & 3;     // group 0..31, 4 lanes/group

    __shared__ float Wk[G_ * GSW_];               // 18.9 KB, [g][k][d] (+bias k=8)
    __shared__ __align__(16) float swl[2][2][D_]; // [buf][wave][d] s-partials
    __shared__ float esw[2][2];                   // [buf][wave] exp-sum partials

    // ---- x preload: 2 aligned float4 + 1 scalar per k (lane c owns
    //      s in {4c..4c+3, 16+4c..19+4c, 32+c}) ----
    float xv[8][9];
    {
        const float* xb = x + (size_t)b * 9216 + (size_t)g * 288 + 4 * c;
        #pragma unroll
        for (int k = 0; k < 8; ++k) {
            const float4 a0 = *(const float4*)(xb + k * 36);
            const float4 a1 = *(const float4*)(xb + k * 36 + 16);
            xv[k][0] = a0.x; xv[k][1] = a0.y; xv[k][2] = a0.z; xv[k][3] = a0.w;
            xv[k][4] = a1.x; xv[k][5] = a1.y; xv[k][6] = a1.z; xv[k][7] = a1.w;
            xv[k][8] = xb[k * 36 + 32 - 3 * c];   // = row + 32 + c
        }
    }

    // ---- stage Wk transposed ([g][k][d]) + bias as k=8 row ----
    #pragma unroll
    for (int rr = 0; rr < 4; ++rr) {
        const int idx = t + rr * NT_;
        const int gg = idx >> 4, d = idx & 15;
        const float* src = Wt + (size_t)gg * 1280 + j * 128 + d * 8;
        const float4 a0 = *(const float4*)(src);
        const float4 a1 = *(const float4*)(src + 4);
        float* dst = Wk + gg * GSW_ + d;
        dst[0]   = a0.x; dst[16]  = a0.y; dst[32]  = a0.z; dst[48]  = a0.w;
        dst[64]  = a1.x; dst[80]  = a1.y; dst[96]  = a1.z; dst[112] = a1.w;
        dst[128] = bias[gg * 160 + j * 16 + d];
    }
    __syncthreads();                               // barrier 0 (staging)

    float b_loc[9] = {0.f,0.f,0.f,0.f,0.f,0.f,0.f,0.f,0.f};
    const float EPS = 2.220446049250313e-16f;

    #pragma unroll 1
    for (int it = 0; it < 3; ++it) {
        const int kb = it & 1;

        // ---- e-weighted x sums over this thread's 9 s's ----
        float yp[8] = {0.f,0.f,0.f,0.f,0.f,0.f,0.f,0.f};
        float esum = 0.f;
        if (it == 0) {
            #pragma unroll
            for (int q = 0; q < 9; ++q) {
                #pragma unroll
                for (int k = 0; k < 8; ++k) yp[k] += xv[k][q];
            }
        } else {
            #pragma unroll
            for (int q = 0; q < 9; ++q) {
                const float e = __expf(b_loc[q]);
                esum += e;
                #pragma unroll
                for (int k = 0; k < 8; ++k) yp[k] += e * xv[k][q];
            }
        }
        // quad reduce via DPP: every lane gets y[g][k] and C_g
        #pragma unroll
        for (int k = 0; k < 8; ++k) {
            yp[k] = dpp_add_x1(yp[k]);
            yp[k] = dpp_add_x2(yp[k]);
        }
        if (it > 0) { esum = dpp_add_x1(esum); esum = dpp_add_x2(esum); }
        const float cg = (it == 0) ? 36.f : esum;

        // ---- per-lane s-partial for d = 4c..4c+3 over its group g ----
        float part[4];
        const float* wg = Wk + g * GSW_ + 4 * c;
        {
            const float4 wb = *(const float4*)(wg + 128);   // bias row (k=8)
            part[0] = wb.x * cg; part[1] = wb.y * cg;
            part[2] = wb.z * cg; part[3] = wb.w * cg;
            #pragma unroll
            for (int k = 0; k < 8; ++k) {
                const float4 wv = *(const float4*)(wg + k * 16);
                part[0] += wv.x * yp[k]; part[1] += wv.y * yp[k];
                part[2] += wv.z * yp[k]; part[3] += wv.w * yp[k];
            }
        }
        // reduce over the wave's 16 groups: bits 2..3 via DPP row_ror:4/8
        // (rotation == xor for full-group sums), bits 4..5 via shfl
        #pragma unroll
        for (int m = 0; m < 4; ++m) {
            part[m] = dpp_add_ror4(part[m]);
            part[m] = dpp_add_ror8(part[m]);
            part[m] += __shfl_xor(part[m], 16);
            part[m] += __shfl_xor(part[m], 32);
        }
        if (it > 0) {
            esum = dpp_add_ror4(esum);
            esum = dpp_add_ror8(esum);
            esum += __shfl_xor(esum, 16);
            esum += __shfl_xor(esum, 32);
        }
        // lanes 0..3 hold s_w[4c..4c+3] (c == lane there)
        if (lane < 4) {
            float4 pw; pw.x = part[0]; pw.y = part[1]; pw.z = part[2]; pw.w = part[3];
            *(float4*)(&swl[kb][wid][4 * lane]) = pw;
            if (lane == 0) esw[kb][wid] = esum;
        }
        __syncthreads();                           // 1 barrier per iter

        const float denom = (it == 0) ? 1152.f : (esw[kb][0] + esw[kb][1]);

        // ---- this lane's s d-slice (broadcast b128 reads) ----
        const float4 sa = *(const float4*)(&swl[kb][0][4 * c]);
        const float4 sb = *(const float4*)(&swl[kb][1][4 * c]);
        float s4[4];
        s4[0] = sa.x + sb.x; s4[1] = sa.y + sb.y;
        s4[2] = sa.z + sb.z; s4[3] = sa.w + sb.w;

        // ssq: slice partial + DPP quad reduce (every lane gets full ssq)
        float ssq = s4[0]*s4[0] + s4[1]*s4[1] + s4[2]*s4[2] + s4[3]*s4[3];
        ssq = dpp_add_x1(ssq);
        ssq = dpp_add_x2(ssq);

        const float alpha = 1.f / denom;
        const float n2    = ssq * alpha * alpha;
        const float nrm   = sqrtf(n2);
        const float coeff = (n2 / (1.f + n2)) / (nrm + EPS);
        const float beta  = alpha * coeff;        // v[d] = s_unnorm[d] * beta

        if (it < 2) {
            // ---- u[g,k]: d-slice partial via ONE b128 per k + DPP reduce ----
            const float t0 = s4[0] * beta, t1 = s4[1] * beta;
            const float t2 = s4[2] * beta, t3 = s4[3] * beta;
            float uk[8];
            #pragma unroll
            for (int k = 0; k < 8; ++k) {
                const float4 wv = *(const float4*)(wg + k * 16);
                float uu = t0 * wv.x + t1 * wv.y + t2 * wv.z + t3 * wv.w;
                uu = dpp_add_x1(uu);
                uk[k] = dpp_add_x2(uu);
            }
            float u8;
            {
                const float4 wb = *(const float4*)(wg + 128);
                u8 = t0 * wb.x + t1 * wb.y + t2 * wb.z + t3 * wb.w;
                u8 = dpp_add_x1(u8);
                u8 = dpp_add_x2(u8);
            }
            // ---- b_i += u . x_i + u_bias (lane-local) ----
            #pragma unroll
            for (int q = 0; q < 9; ++q) {
                float acc = u8;
                #pragma unroll
                for (int k = 0; k < 8; ++k) acc += uk[k] * xv[k][q];
                b_loc[q] += acc;
            }
        } else {
            if (t < D_) {
                const float sd = swl[kb][0][t] + swl[kb][1][t];
                out[(size_t)bj * D_ + t] = sd * beta;
            }
        }
    }
}

extern "C" void kernel_launch(void* const* d_in, const int* in_sizes, int n_in,
                              void* d_out, int out_size, void* d_ws, size_t ws_size,
                              hipStream_t stream) {
    const float* x    = (const float*)d_in[0];
    const float* Wt   = (const float*)d_in[1];
    const float* bias = (const float*)d_in[2];
    float* out        = (float*)d_out;

    const int bs = in_sizes[0] / 9216;   // 256
    dim3 grid(bs * J_);                  // 2560
    dim3 block(NT_);
    caps_route_kernel<<<grid, block, 0, stream>>>(x, Wt, bias, out);
}

// Round 16
// 21.075 us; speedup vs baseline: 1.4650x; 1.1251x over previous
//
#include <hip/hip_runtime.h>
#include <math.h>

// CapLayer fused, R16 = R15 + v_pk_fma_f32 (packed dual-fp32 VOP3P) on the
// FMA-dominant loops. VALU model: R15 ~790 ops/thread ~1580cyc/wave x20 waves
// = ~13us/CU, now the largest pipe (DS cut to ~800cyc by R13/R15). The
// q-dimension packs free: float4 x-loads already hold q-pairs in adjacent
// VGPRs. b_loc stored AS pairs -> b-update accumulates via pk_fma with no
// horizontal adds. s-partial/u-phase/reduces unchanged from R15.
// NO launch_bounds min-waves (R2/R3/R7: caps below working set spill).

#define G_    32
#define J_    10
#define D_    16
#define NT_   128
#define GSW_  148

typedef float v2f __attribute__((ext_vector_type(2)));

__device__ __forceinline__ v2f pk_fma(v2f a, v2f b, v2f c) {
    v2f d;
    asm("v_pk_fma_f32 %0, %1, %2, %3" : "=v"(d) : "v"(a), "v"(b), "v"(c));
    return d;
}
__device__ __forceinline__ v2f pk_add(v2f a, v2f b) {
    v2f d;
    asm("v_pk_add_f32 %0, %1, %2" : "=v"(d) : "v"(a), "v"(b));
    return d;
}
__device__ __forceinline__ v2f pk_mul(v2f a, v2f b) {
    v2f d;
    asm("v_pk_mul_f32 %0, %1, %2" : "=v"(d) : "v"(a), "v"(b));
    return d;
}
__device__ __forceinline__ v2f mk2(float a, float b) { v2f r; r.x = a; r.y = b; return r; }

__device__ __forceinline__ float dpp_add_x1(float v) {   // v += lane^1
    const int s = __builtin_amdgcn_update_dpp(0, __float_as_int(v), 0xB1, 0xF, 0xF, true);
    return v + __int_as_float(s);
}
__device__ __forceinline__ float dpp_add_x2(float v) {   // v += lane^2
    const int s = __builtin_amdgcn_update_dpp(0, __float_as_int(v), 0x4E, 0xF, 0xF, true);
    return v + __int_as_float(s);
}
__device__ __forceinline__ float dpp_add_ror4(float v) { // v += row_ror:4
    const int s = __builtin_amdgcn_update_dpp(0, __float_as_int(v), 0x124, 0xF, 0xF, true);
    return v + __int_as_float(s);
}
__device__ __forceinline__ float dpp_add_ror8(float v) { // v += row_ror:8
    const int s = __builtin_amdgcn_update_dpp(0, __float_as_int(v), 0x128, 0xF, 0xF, true);
    return v + __int_as_float(s);
}

__global__ __launch_bounds__(NT_) void caps_route_kernel(
    const float* __restrict__ x,     // (b, g*8+k, s) flat b*9216 + g*288 + k*36 + s
    const float* __restrict__ Wt,    // (g, j*16+d, k) flat g*1280 + (j*16+d)*8 + k
    const float* __restrict__ bias,  // g*160 + j*16 + d
    float* __restrict__ out)         // (b, j, d)
{
    const int B = blockIdx.x, nwg = gridDim.x;
    const int bj = ((nwg & 7) == 0) ? (B & 7) * (nwg >> 3) + (B >> 3) : B;
    const int b = bj / J_, j = bj - b * J_;
    const int t = threadIdx.x;
    const int lane = t & 63, wid = t >> 6;
    const int g = t >> 2, c = t & 3;     // group 0..31, 4 lanes/group

    __shared__ float Wk[G_ * GSW_];               // 18.9 KB, [g][k][d] (+bias k=8)
    __shared__ __align__(16) float swl[2][2][D_]; // [buf][wave][d] s-partials
    __shared__ float esw[2][2];                   // [buf][wave] exp-sum partials

    // ---- x preload as q-pairs: xq2[k][p] = (x[q=2p], x[q=2p+1]), xq8 scalar ----
    v2f  xq2[8][4];
    float xq8[8];
    {
        const float* xb = x + (size_t)b * 9216 + (size_t)g * 288 + 4 * c;
        #pragma unroll
        for (int k = 0; k < 8; ++k) {
            const float4 a0 = *(const float4*)(xb + k * 36);
            const float4 a1 = *(const float4*)(xb + k * 36 + 16);
            xq2[k][0] = mk2(a0.x, a0.y); xq2[k][1] = mk2(a0.z, a0.w);
            xq2[k][2] = mk2(a1.x, a1.y); xq2[k][3] = mk2(a1.z, a1.w);
            xq8[k] = xb[k * 36 + 32 - 3 * c];   // = row + 32 + c
        }
    }

    // ---- stage Wk transposed ([g][k][d]) + bias as k=8 row ----
    #pragma unroll
    for (int rr = 0; rr < 4; ++rr) {
        const int idx = t + rr * NT_;
        const int gg = idx >> 4, d = idx & 15;
        const float* src = Wt + (size_t)gg * 1280 + j * 128 + d * 8;
        const float4 a0 = *(const float4*)(src);
        const float4 a1 = *(const float4*)(src + 4);
        float* dst = Wk + gg * GSW_ + d;
        dst[0]   = a0.x; dst[16]  = a0.y; dst[32]  = a0.z; dst[48]  = a0.w;
        dst[64]  = a1.x; dst[80]  = a1.y; dst[96]  = a1.z; dst[112] = a1.w;
        dst[128] = bias[gg * 160 + j * 16 + d];
    }
    __syncthreads();                               // barrier 0 (staging)

    // b-logits as pairs (q=2p, 2p+1) + scalar q=8
    v2f  bl2[4] = {mk2(0.f,0.f), mk2(0.f,0.f), mk2(0.f,0.f), mk2(0.f,0.f)};
    float bl8 = 0.f;
    const float EPS = 2.220446049250313e-16f;

    #pragma unroll 1
    for (int it = 0; it < 3; ++it) {
        const int kb = it & 1;

        // ---- e-weighted x sums over this thread's 9 s's (packed) ----
        float yp[8];
        float esum = 0.f;
        if (it == 0) {
            #pragma unroll
            for (int k = 0; k < 8; ++k) {
                v2f acc = pk_add(xq2[k][0], xq2[k][1]);
                acc = pk_add(acc, xq2[k][2]);
                acc = pk_add(acc, xq2[k][3]);
                yp[k] = acc.x + acc.y + xq8[k];
            }
        } else {
            v2f e2[4];
            #pragma unroll
            for (int p = 0; p < 4; ++p)
                e2[p] = mk2(__expf(bl2[p].x), __expf(bl2[p].y));
            const float e8 = __expf(bl8);
            v2f es2 = pk_add(pk_add(e2[0], e2[1]), pk_add(e2[2], e2[3]));
            esum = es2.x + es2.y + e8;
            #pragma unroll
            for (int k = 0; k < 8; ++k) {
                v2f acc = pk_mul(e2[0], xq2[k][0]);
                acc = pk_fma(e2[1], xq2[k][1], acc);
                acc = pk_fma(e2[2], xq2[k][2], acc);
                acc = pk_fma(e2[3], xq2[k][3], acc);
                yp[k] = acc.x + acc.y + e8 * xq8[k];
            }
        }
        // quad reduce via DPP: every lane gets y[g][k] and C_g
        #pragma unroll
        for (int k = 0; k < 8; ++k) {
            yp[k] = dpp_add_x1(yp[k]);
            yp[k] = dpp_add_x2(yp[k]);
        }
        if (it > 0) { esum = dpp_add_x1(esum); esum = dpp_add_x2(esum); }
        const float cg = (it == 0) ? 36.f : esum;

        // ---- per-lane s-partial for d = 4c..4c+3 over its group g ----
        float part[4];
        const float* wg = Wk + g * GSW_ + 4 * c;
        {
            const float4 wb = *(const float4*)(wg + 128);   // bias row (k=8)
            part[0] = wb.x * cg; part[1] = wb.y * cg;
            part[2] = wb.z * cg; part[3] = wb.w * cg;
            #pragma unroll
            for (int k = 0; k < 8; ++k) {
                const float4 wv = *(const float4*)(wg + k * 16);
                part[0] += wv.x * yp[k]; part[1] += wv.y * yp[k];
                part[2] += wv.z * yp[k]; part[3] += wv.w * yp[k];
            }
        }
        // reduce over the wave's 16 groups: ror4/ror8 DPP + xor16/32 shfl
        #pragma unroll
        for (int m = 0; m < 4; ++m) {
            part[m] = dpp_add_ror4(part[m]);
            part[m] = dpp_add_ror8(part[m]);
            part[m] += __shfl_xor(part[m], 16);
            part[m] += __shfl_xor(part[m], 32);
        }
        if (it > 0) {
            esum = dpp_add_ror4(esum);
            esum = dpp_add_ror8(esum);
            esum += __shfl_xor(esum, 16);
            esum += __shfl_xor(esum, 32);
        }
        // lanes 0..3 hold s_w[4c..4c+3] (c == lane there)
        if (lane < 4) {
            float4 pw; pw.x = part[0]; pw.y = part[1]; pw.z = part[2]; pw.w = part[3];
            *(float4*)(&swl[kb][wid][4 * lane]) = pw;
            if (lane == 0) esw[kb][wid] = esum;
        }
        __syncthreads();                           // 1 barrier per iter

        const float denom = (it == 0) ? 1152.f : (esw[kb][0] + esw[kb][1]);

        // ---- this lane's s d-slice (broadcast b128 reads) ----
        const float4 sa = *(const float4*)(&swl[kb][0][4 * c]);
        const float4 sb = *(const float4*)(&swl[kb][1][4 * c]);
        float s4[4];
        s4[0] = sa.x + sb.x; s4[1] = sa.y + sb.y;
        s4[2] = sa.z + sb.z; s4[3] = sa.w + sb.w;

        // ssq: slice partial + DPP quad reduce (every lane gets full ssq)
        float ssq = s4[0]*s4[0] + s4[1]*s4[1] + s4[2]*s4[2] + s4[3]*s4[3];
        ssq = dpp_add_x1(ssq);
        ssq = dpp_add_x2(ssq);

        const float alpha = 1.f / denom;
        const float n2    = ssq * alpha * alpha;
        const float nrm   = sqrtf(n2);
        const float coeff = (n2 / (1.f + n2)) / (nrm + EPS);
        const float beta  = alpha * coeff;        // v[d] = s_unnorm[d] * beta

        if (it < 2) {
            // ---- u[g,k]: d-slice partial via ONE b128 per k + DPP reduce ----
            const float t0 = s4[0] * beta, t1 = s4[1] * beta;
            const float t2 = s4[2] * beta, t3 = s4[3] * beta;
            float uk[8];
            #pragma unroll
            for (int k = 0; k < 8; ++k) {
                const float4 wv = *(const float4*)(wg + k * 16);
                float uu = t0 * wv.x + t1 * wv.y + t2 * wv.z + t3 * wv.w;
                uu = dpp_add_x1(uu);
                uk[k] = dpp_add_x2(uu);
            }
            float u8;
            {
                const float4 wb = *(const float4*)(wg + 128);
                u8 = t0 * wb.x + t1 * wb.y + t2 * wb.z + t3 * wb.w;
                u8 = dpp_add_x1(u8);
                u8 = dpp_add_x2(u8);
            }
            // ---- b-update, packed: bl2[p] += u8 + sum_k uk[k] * xq2[k][p] ----
            const v2f u82 = mk2(u8, u8);
            #pragma unroll
            for (int p = 0; p < 4; ++p) bl2[p] = pk_add(bl2[p], u82);
            #pragma unroll
            for (int k = 0; k < 8; ++k) {
                const v2f uk2 = mk2(uk[k], uk[k]);
                #pragma unroll
                for (int p = 0; p < 4; ++p)
                    bl2[p] = pk_fma(uk2, xq2[k][p], bl2[p]);
            }
            float acc8 = u8;
            #pragma unroll
            for (int k = 0; k < 8; ++k) acc8 += uk[k] * xq8[k];
            bl8 += acc8;
        } else {
            if (t < D_) {
                const float sd = swl[kb][0][t] + swl[kb][1][t];
                out[(size_t)bj * D_ + t] = sd * beta;
            }
        }
    }
}

extern "C" void kernel_launch(void* const* d_in, const int* in_sizes, int n_in,
                              void* d_out, int out_size, void* d_ws, size_t ws_size,
                              hipStream_t stream) {
    const float* x    = (const float*)d_in[0];
    const float* Wt   = (const float*)d_in[1];
    const float* bias = (const float*)d_in[2];
    float* out        = (float*)d_out;

    const int bs = in_sizes[0] / 9216;   // 256
    dim3 grid(bs * J_);                  // 2560
    dim3 block(NT_);
    caps_route_kernel<<<grid, block, 0, stream>>>(x, Wt, bias, out);
}